// Round 5
// baseline (8768.552 us; speedup 1.0000x reference)
//
#include <hip/hip_runtime.h>

#define S_LEN 128
#define B_N   1024
#define T_LEN 96
#define E_DIM 64
#define HH    100
#define H_DIM 200
#define ACT_D 32
#define FLD_D 8
#define ATT_D 200
#define DEC_IN 440          // 32 + 200 + 8 + 200
#define KTOT  640           // DEC_IN + H_DIM
#define G4H   800           // 4*H
#define G4HH  400           // 4*HH
#define KH_PAD 224          // wattn k-pad (7*32)
#define KC_PAD 416          // [ctx|h] k-pad for s_att MFMA
#define NCOL_PAD 208        // 13*16 col pad
#define EK_ROWS 208         // enc_ks global k rows
#define EK_SLD 136          // enc LDS s-stride (f16): 272 B = 17*16, odd*16 banks
// decoder LDS strides (f16 elems)
#define XA_LD 648
#define HG_LD 232
#define GA_LD 232
#define CAT_LD 424
#define ROWS 2              // batch rows per decoder block

typedef unsigned int  u32;
typedef unsigned short u16;
typedef _Float16 f16;
typedef _Float16 f16x8 __attribute__((ext_vector_type(8)));
typedef _Float16 f16x4 __attribute__((ext_vector_type(4)));
typedef float    f32x4 __attribute__((ext_vector_type(4)));

#define MFMA16(a,b,c) __builtin_amdgcn_mfma_f32_16x16x32_f16((a),(b),(c),0,0,0)

static __device__ __forceinline__ float lo_bf(u32 u){ union{u32 i; float f;}v; v.i = u<<16; return v.f; }
static __device__ __forceinline__ float hi_bf(u32 u){ union{u32 i; float f;}v; v.i = u & 0xffff0000u; return v.f; }
static __device__ __forceinline__ float sigf(float x){
  x = fminf(30.f, fmaxf(-30.f, x));
  return 1.f/(1.f + __expf(-x));
}
static __device__ __forceinline__ float tanhf_(float x){
  x = fminf(15.f, fmaxf(-15.f, x));
  float e = __expf(-2.f*x);
  return (1.f - e)/(1.f + e);
}

// ---------- prep kernels ----------
static __device__ __forceinline__ u16 f2bf(float f){
  union{float f; u32 i;} v; v.f = f;
  u32 r = v.i + 0x7fffu + ((v.i >> 16) & 1u);
  return (u16)(r >> 16);
}
__global__ void k_prep(u16* __restrict__ dst, const float* __restrict__ src,
                       int K, int C, int sk, int sc)
{
  int idx = blockIdx.x*256 + threadIdx.x;
  if (idx >= K*C) return;
  int k = idx / C, c = idx - k*C;
  dst[(size_t)(k>>2)*(4*C) + 4*c + (k&3)] = f2bf(src[(size_t)k*sk + (size_t)c*sc]);
}

__global__ void k_pack16(f16* __restrict__ dst, const float* __restrict__ src,
                         int Kld, int koff, int C, int K, int sk, int sc)
{
  int idx = blockIdx.x*256 + threadIdx.x;
  if (idx >= C*K) return;
  int c = idx / K, k = idx - c*K;
  dst[(size_t)c*Kld + koff + k] = (f16)src[(size_t)k*sk + (size_t)c*sc];
}

__global__ void k_zf16(f16* __restrict__ dst, int n)
{
  int idx = blockIdx.x*256 + threadIdx.x;
  if (idx < n) dst[idx] = (f16)0.f;
}

// Transpose enc_sk[b][s][200] -> enc_ks[b][k][128]; one block per b.
__global__ __launch_bounds__(256) void k_transpose(
    const f16* __restrict__ enc_sk, f16* __restrict__ enc_ks)
{
  __shared__ f16 ld[H_DIM][136];
  const int b = blockIdx.x, tid = threadIdx.x;
  const f16* src = enc_sk + (size_t)b*S_LEN*H_DIM;
  for (int idx = tid; idx < S_LEN*(H_DIM/4); idx += 256) {
    int s = idx / (H_DIM/4), jc = idx - s*(H_DIM/4);
    f16x4 v = *(const f16x4*)(src + (size_t)s*H_DIM + 4*jc);
    #pragma unroll
    for (int i = 0; i < 4; ++i) ld[4*jc + i][s] = v[i];
  }
  __syncthreads();
  f16* dst = enc_ks + (size_t)b*EK_ROWS*S_LEN;
  for (int idx = tid; idx < H_DIM*(S_LEN/8); idx += 256) {
    int k = idx / (S_LEN/8), so = idx - k*(S_LEN/8);
    f16x8 v;
    #pragma unroll
    for (int i = 0; i < 8; ++i) v[i] = ld[k][8*so + i];
    *(f16x8*)(dst + (size_t)k*S_LEN + 8*so) = v;
  }
}

// ---------- Bi-LSTM encoder ----------
__global__ __launch_bounds__(512) void k_encoder(
    const int* __restrict__ sentences, const float* __restrict__ src_emb,
    const float* __restrict__ b_f, const float* __restrict__ b_b,
    const uint2* __restrict__ wihF, const uint2* __restrict__ whhF,
    const uint2* __restrict__ wihB, const uint2* __restrict__ whhB,
    f16* __restrict__ enc_sk,              // [B][S][200] f16
    float* __restrict__ hTf, float* __restrict__ cTf,
    float* __restrict__ hTb, float* __restrict__ cTb)
{
  const int tid = threadIdx.x;
  const int dir = blockIdx.x >> 7;
  const int bg  = blockIdx.x & 127;
  const int b0  = bg * 8;

  __shared__ alignas(16) float xs[8][E_DIM];
  __shared__ alignas(16) float hs[8][HH];
  __shared__ alignas(16) float zs[8][G4HH];

  const uint2* wih = dir ? wihB : wihF;
  const uint2* whh = dir ? whhB : whhF;
  const float* bias = dir ? b_b : b_f;

  for (int idx = tid; idx < 8*HH; idx += 512) ((float*)hs)[idx] = 0.f;
  float c0r = 0.f, c1r = 0.f;

  const int col = tid;
  const bool act = (col < G4HH);
  const float bias0 = act ? bias[col] : 0.f;

  __syncthreads();

  for (int step = 0; step < S_LEN; ++step) {
    const int s = dir ? (S_LEN-1-step) : step;
    {
      int r = tid >> 6, e = tid & 63;
      int tok = sentences[s*B_N + (b0 + r)];
      xs[r][e] = src_emb[(size_t)tok*E_DIM + e];
    }
    __syncthreads();

    if (act) {
      float acc[8];
      #pragma unroll
      for (int r = 0; r < 8; ++r) acc[r] = bias0;
      #pragma unroll 2
      for (int k4 = 0; k4 < E_DIM/4; ++k4) {
        uint2 u = wih[k4*G4HH + col];
        float w0 = lo_bf(u.x), w1 = hi_bf(u.x), w2 = lo_bf(u.y), w3 = hi_bf(u.y);
        #pragma unroll
        for (int r = 0; r < 8; ++r) {
          float4 xv = *(const float4*)&xs[r][4*k4];
          acc[r] += xv.x*w0 + xv.y*w1 + xv.z*w2 + xv.w*w3;
        }
      }
      #pragma unroll 2
      for (int k4 = 0; k4 < HH/4; ++k4) {
        uint2 u = whh[k4*G4HH + col];
        float w0 = lo_bf(u.x), w1 = hi_bf(u.x), w2 = lo_bf(u.y), w3 = hi_bf(u.y);
        #pragma unroll
        for (int r = 0; r < 8; ++r) {
          float4 hv = *(const float4*)&hs[r][4*k4];
          acc[r] += hv.x*w0 + hv.y*w1 + hv.z*w2 + hv.w*w3;
        }
      }
      #pragma unroll
      for (int r = 0; r < 8; ++r) zs[r][col] = acc[r];
    }
    __syncthreads();

    {
      int r = tid / HH, j = tid - r*HH;
      float c = sigf(zs[r][HH+j])*c0r + sigf(zs[r][j])*tanhf_(zs[r][2*HH+j]);
      float h = sigf(zs[r][3*HH+j])*tanhf_(c);
      c0r = c;
      hs[r][j] = h;
      enc_sk[((size_t)(b0+r)*S_LEN + s)*H_DIM + dir*HH + j] = (f16)h;
      if (tid < 8*HH - 512) {
        int idx2 = tid + 512;
        int r2 = idx2 / HH, j2 = idx2 - r2*HH;
        float c2 = sigf(zs[r2][HH+j2])*c1r + sigf(zs[r2][j2])*tanhf_(zs[r2][2*HH+j2]);
        float h2 = sigf(zs[r2][3*HH+j2])*tanhf_(c2);
        c1r = c2;
        hs[r2][j2] = h2;
        enc_sk[((size_t)(b0+r2)*S_LEN + s)*H_DIM + dir*HH + j2] = (f16)h2;
      }
    }
    __syncthreads();
  }

  float* hT = dir ? hTb : hTf;
  float* cT = dir ? cTb : cTf;
  {
    int r = tid / HH, j = tid - r*HH;
    hT[(b0+r)*HH + j] = hs[r][j];
    cT[(b0+r)*HH + j] = c0r;
    if (tid < 8*HH - 512) {
      int idx2 = tid + 512; int r2 = idx2 / HH, j2 = idx2 - r2*HH;
      hT[(b0+r2)*HH + j2] = hs[r2][j2];
      cT[(b0+r2)*HH + j2] = c1r;
    }
  }
}

// ---------- Decoder: 2 rows/block, 512 blocks, enc pinned in LDS ----------
__global__ __launch_bounds__(512, 2) void k_decoder(
  const int* __restrict__ is_prod, const int* __restrict__ prod_ids,
  const int* __restrict__ prim_ids, const int* __restrict__ field_ids,
  const int* __restrict__ parent_t,
  const float* __restrict__ actprod_emb, const float* __restrict__ prim_emb,
  const float* __restrict__ field_emb, const float* __restrict__ b_d,
  const f16* __restrict__ wall,    // [800][640]
  const f16* __restrict__ wattn,   // [208][224]  B[j][n]=W_attn[n][j]
  const f16* __restrict__ wav,     // [208][416]
  const f16* __restrict__ enc_ks,  // [B][208][128]
  const float* __restrict__ hTf, const float* __restrict__ cTf,
  const float* __restrict__ hTb, const float* __restrict__ cTb,
  f16* __restrict__ Hbuf, float* __restrict__ out)
{
  const int tid  = threadIdx.x;
  const int lane = tid & 63;
  const int wid  = tid >> 6;          // 8 waves
  const int b0   = blockIdx.x * ROWS;
  const int arow = lane & 15;
  const int aoff = (lane >> 4) * 8;

  __shared__ alignas(16) f16   encl[ROWS][H_DIM][EK_SLD];  // ~108.8 KB, resident all steps
  __shared__ alignas(16) f16   xa[ROWS][XA_LD];    // [a32|s_att200|nft8|parent200|h200]
  __shared__ alignas(16) f16   hg[ROWS][HG_LD];    // h (zero-padded to 232)
  __shared__ alignas(16) f16   gA[ROWS][GA_LD];    // g = W_attn^T h
  __shared__ alignas(16) f16   cat[ROWS][CAT_LD];  // [ctx200|h200|pad16]
  __shared__ alignas(16) f16   aw_sh[ROWS][S_LEN];
  __shared__ alignas(16) float zs[ROWS][G4H];
  __shared__ float biasd[G4H];

  // ---- init
  for (int idx = tid; idx < G4H; idx += 512) biasd[idx] = b_d[idx];
  for (int idx = tid; idx < ROWS*(HG_LD-H_DIM); idx += 512) {
    int n = HG_LD-H_DIM; hg[idx/n][H_DIM + idx%n] = (f16)0.f;
  }
  for (int idx = tid; idx < ROWS*(GA_LD-H_DIM); idx += 512) {
    int n = GA_LD-H_DIM; gA[idx/n][H_DIM + idx%n] = (f16)0.f;
  }
  for (int idx = tid; idx < ROWS*(CAT_LD-2*H_DIM); idx += 512) {
    int n = CAT_LD-2*H_DIM; cat[idx/n][2*H_DIM + idx%n] = (f16)0.f;
  }
  for (int idx = tid; idx < ROWS*DEC_IN; idx += 512) {   // t=0 input = zeros
    xa[idx/DEC_IN][idx%DEC_IN] = (f16)0.f;
  }
  // load enc slice into LDS (one-time): [r][k][s], coalesced 16B
  for (int idx = tid; idx < ROWS*H_DIM*(S_LEN/8); idx += 512) {
    int r  = idx / (H_DIM*(S_LEN/8));
    int rm = idx - r*(H_DIM*(S_LEN/8));
    int k  = rm / (S_LEN/8), so = rm - k*(S_LEN/8);
    *(f16x8*)&encl[r][k][8*so] =
      *(const f16x8*)(enc_ks + ((size_t)(b0+r)*EK_ROWS + k)*S_LEN + 8*so);
  }
  for (int idx = tid; idx < ROWS*H_DIM; idx += 512) {
    int r = idx / H_DIM, j = idx - r*H_DIM; int b = b0 + r;
    float v;
    if (b < 512) v = (j < HH) ? hTf[(2*b)*HH + j] : hTf[(2*b+1)*HH + (j-HH)];
    else { int bb = b-512; v = (j < HH) ? hTb[(2*bb)*HH + j] : hTb[(2*bb+1)*HH + (j-HH)]; }
    f16 hv = (f16)v;
    xa[r][DEC_IN + j] = hv; hg[r][j] = hv; cat[r][H_DIM + j] = hv;
  }
  float cst = 0.f;
  if (tid < ROWS*H_DIM) {
    int r = tid / H_DIM, j = tid - r*H_DIM; int b = b0 + r;
    if (b < 512) cst = (j < HH) ? cTf[(2*b)*HH + j] : cTf[(2*b+1)*HH + (j-HH)];
    else { int bb = b-512; cst = (j < HH) ? cTb[(2*bb)*HH + j] : cTb[(2*bb+1)*HH + (j-HH)]; }
  }
  __syncthreads();

  for (int t = 0; t < T_LEN; ++t) {
    // ---- z = [inp|h] @ wall + b_d via MFMA (20 k-tiles, 50 n-tiles over 8 waves)
    {
      f16x8 afr[20];
      #pragma unroll
      for (int kk = 0; kk < 20; ++kk) {
        f16x8 v = {0,0,0,0,0,0,0,0};
        if (arow < ROWS) v = *(const f16x8*)&xa[arow][kk*32 + aoff];
        afr[kk] = v;
      }
      for (int tt = wid; tt < 50; tt += 8) {
        int c = tt*16 + arow;
        float bv = biasd[c];
        f32x4 acc = {bv, bv, bv, bv};
        const f16* p = wall + (size_t)c*KTOT + aoff;
        #pragma unroll
        for (int kk = 0; kk < 20; ++kk)
          acc = MFMA16(afr[kk], *(const f16x8*)(p + kk*32), acc);
        if (lane < 16) {      // C rows 0..3 live in quad 0
          #pragma unroll
          for (int i2 = 0; i2 < ROWS; ++i2) zs[i2][c] = acc[i2];
        }
      }
    }
    __syncthreads();

    // ---- LSTM cell (i,f,g,o)
    if (tid < ROWS*H_DIM) {
      int r = tid / H_DIM, j = tid - r*H_DIM;
      float c = sigf(zs[r][H_DIM+j])*cst + sigf(zs[r][j])*tanhf_(zs[r][2*H_DIM+j]);
      float h = sigf(zs[r][3*H_DIM+j])*tanhf_(c);
      cst = c;
      f16 hv = (f16)h;
      xa[r][DEC_IN + j] = hv; hg[r][j] = hv; cat[r][H_DIM + j] = hv;
      Hbuf[((size_t)t*B_N + (b0+r))*H_DIM + j] = hv;
    }
    __syncthreads();

    // ---- g = W_attn^T h via MFMA (7 k-tiles, 13 n-tiles over 8 waves)
    {
      f16x8 ga[7];
      #pragma unroll
      for (int kk = 0; kk < 7; ++kk) {
        f16x8 v = {0,0,0,0,0,0,0,0};
        if (arow < ROWS) v = *(const f16x8*)&hg[arow][kk*32 + aoff];
        ga[kk] = v;
      }
      #pragma unroll
      for (int pass = 0; pass < 2; ++pass) {
        int tt = wid + pass*8;
        if (tt < 13) {
          int c = tt*16 + arow;
          f32x4 acc = {0.f,0.f,0.f,0.f};
          const f16* p = wattn + (size_t)c*KH_PAD + aoff;
          #pragma unroll
          for (int kk = 0; kk < 7; ++kk)
            acc = MFMA16(ga[kk], *(const f16x8*)(p + kk*32), acc);
          if (lane < 16 && c < H_DIM) {
            #pragma unroll
            for (int i2 = 0; i2 < ROWS; ++i2) gA[i2][c] = (f16)acc[i2];
          }
        }
      }
    }
    __syncthreads();

    // ---- scores + softmax from LDS enc: waves 0..ROWS-1, one per row
    if (wid < ROWS) {
      const int r = wid;
      const int sl = lane & 15, kp = lane >> 4;   // 16 s-octets x 4 k-quarters
      float acc[8] = {0.f,0.f,0.f,0.f,0.f,0.f,0.f,0.f};
      #pragma unroll 5
      for (int i = 0; i < 50; ++i) {
        int k = kp*50 + i;
        f16x8 e8 = *(const f16x8*)&encl[r][k][8*sl];
        float gf = (float)gA[r][k];
        #pragma unroll
        for (int q = 0; q < 8; ++q) acc[q] += gf * (float)e8[q];
      }
      #pragma unroll
      for (int q = 0; q < 8; ++q) {
        acc[q] += __shfl_xor(acc[q], 16);
        acc[q] += __shfl_xor(acc[q], 32);
      }
      float m = acc[0];
      #pragma unroll
      for (int q = 1; q < 8; ++q) m = fmaxf(m, acc[q]);
      #pragma unroll
      for (int d = 1; d < 16; d <<= 1) m = fmaxf(m, __shfl_xor(m, d));
      float e[8], sm = 0.f;
      #pragma unroll
      for (int q = 0; q < 8; ++q) { e[q] = __expf(acc[q] - m); sm += e[q]; }
      #pragma unroll
      for (int d = 1; d < 16; d <<= 1) sm += __shfl_xor(sm, d);
      float rd = 1.f / sm;
      if (kp == 0) {
        f16x8 w;
        #pragma unroll
        for (int q = 0; q < 8; ++q) w[q] = (f16)(e[q] * rd);
        *(f16x8*)&aw_sh[r][8*sl] = w;
      }
    }
    __syncthreads();

    // ---- ctx via block-diagonal MFMA over LDS enc (K'=(r',s)=256) + stage t+1
    {
      #pragma unroll
      for (int pass = 0; pass < 2; ++pass) {
        int tt = wid + pass*8;
        if (tt < 13) {
          int c = tt*16 + arow;
          f32x4 acc = {0.f,0.f,0.f,0.f};
          #pragma unroll
          for (int kt = 0; kt < 4*ROWS; ++kt) {
            int rp = kt >> 2;
            int s0 = (kt & 3) * 32;
            f16x8 a = {0,0,0,0,0,0,0,0};
            if (arow == rp) a = *(const f16x8*)&aw_sh[rp][s0 + aoff];
            f16x8 bf = {0,0,0,0,0,0,0,0};
            if (c < H_DIM) bf = *(const f16x8*)&encl[rp][c][s0 + aoff];
            acc = MFMA16(a, bf, acc);
          }
          if (lane < 16 && c < H_DIM) {
            #pragma unroll
            for (int i2 = 0; i2 < ROWS; ++i2) cat[i2][c] = (f16)acc[i2];
          }
        }
      }
      // stage a/nft/parent for step t+1 (regions disjoint from s_att/h)
      if (t + 1 < T_LEN) {
        const int tn = t + 1;
        for (int idx = tid; idx < ROWS*DEC_IN; idx += 512) {
          int r = idx / DEC_IN, k = idx - r*DEC_IN;
          if (k >= ACT_D && k < ACT_D + ATT_D) continue;
          int b = b0 + r;
          f16 v;
          if (k < ACT_D) {
            float f = (is_prod[tn*B_N + b] == 1)
              ? actprod_emb[prod_ids[tn*B_N + b]*ACT_D + k]
              : prim_emb[prim_ids[tn*B_N + b]*ACT_D + k];
            v = (f16)f;
          } else if (k < ACT_D + ATT_D + FLD_D) {
            v = (f16)field_emb[field_ids[tn*B_N + b]*FLD_D + (k - ACT_D - ATT_D)];
          } else {
            int pt = parent_t[tn*B_N + b];
            v = Hbuf[((size_t)pt*B_N + b)*H_DIM + (k - (ACT_D+ATT_D+FLD_D))];
          }
          xa[r][k] = v;
        }
      }
    }
    __syncthreads();

    // ---- s_att = tanh([ctx|h] @ wav) via MFMA (13 k-tiles, 13 n-tiles)
    {
      f16x8 sa[13];
      #pragma unroll
      for (int kk = 0; kk < 13; ++kk) {
        f16x8 v = {0,0,0,0,0,0,0,0};
        if (arow < ROWS) v = *(const f16x8*)&cat[arow][kk*32 + aoff];
        sa[kk] = v;
      }
      #pragma unroll
      for (int pass = 0; pass < 2; ++pass) {
        int tt = wid + pass*8;
        if (tt < 13) {
          int c = tt*16 + arow;
          f32x4 acc = {0.f,0.f,0.f,0.f};
          const f16* p = wav + (size_t)c*KC_PAD + aoff;
          #pragma unroll
          for (int kk = 0; kk < 13; ++kk)
            acc = MFMA16(sa[kk], *(const f16x8*)(p + kk*32), acc);
          if (lane < 16 && c < ATT_D) {
            #pragma unroll
            for (int i2 = 0; i2 < ROWS; ++i2) {
              float v = tanhf_(acc[i2]);
              out[((size_t)t*B_N + (b0+i2))*ATT_D + c] = v;
              xa[i2][ACT_D + c] = (f16)v;
            }
          }
        }
      }
    }
    __syncthreads();
  }
}

extern "C" void kernel_launch(void* const* d_in, const int* in_sizes, int n_in,
                              void* d_out, int out_size, void* d_ws, size_t ws_size,
                              hipStream_t stream)
{
  const int*   sentences = (const int*)  d_in[0];
  const int*   is_prod   = (const int*)  d_in[1];
  const int*   prod_ids  = (const int*)  d_in[2];
  const int*   prim_ids  = (const int*)  d_in[3];
  const int*   field_ids = (const int*)  d_in[4];
  const int*   parent_t  = (const int*)  d_in[5];
  const float* src_emb   = (const float*)d_in[6];
  const float* actprod   = (const float*)d_in[7];
  const float* prim_emb  = (const float*)d_in[8];
  const float* field_emb = (const float*)d_in[9];
  const float* Wih_f = (const float*)d_in[10];
  const float* Whh_f = (const float*)d_in[11];
  const float* b_f   = (const float*)d_in[12];
  const float* Wih_b = (const float*)d_in[13];
  const float* Whh_b = (const float*)d_in[14];
  const float* b_b   = (const float*)d_in[15];
  const float* Wih_d = (const float*)d_in[16];
  const float* Whh_d = (const float*)d_in[17];
  const float* b_d   = (const float*)d_in[18];
  const float* W_attn= (const float*)d_in[19];
  const float* W_av  = (const float*)d_in[20];
  (void)in_sizes; (void)n_in; (void)out_size; (void)ws_size;

  char* ws = (char*)d_ws;
  size_t off = 0;
  auto take = [&](size_t bytes) -> void* {
    void* p = ws + off;
    off = (off + bytes + 255) & ~(size_t)255;
    return p;
  };
  u16* wihF = (u16*)take((size_t)64*400*2);
  u16* whhF = (u16*)take((size_t)100*400*2);
  u16* wihB = (u16*)take((size_t)64*400*2);
  u16* whhB = (u16*)take((size_t)100*400*2);
  f16* wall16  = (f16*)take((size_t)800*640*2);
  f16* wattn16 = (f16*)take((size_t)NCOL_PAD*KH_PAD*2);
  f16* wav16   = (f16*)take((size_t)NCOL_PAD*KC_PAD*2);
  f16* enc_sk  = (f16*)take((size_t)B_N*S_LEN*H_DIM*2);
  f16* enc_ks  = (f16*)take((size_t)B_N*EK_ROWS*S_LEN*2);
  float* hTf = (float*)take((size_t)B_N*HH*4);
  float* cTf = (float*)take((size_t)B_N*HH*4);
  float* hTb = (float*)take((size_t)B_N*HH*4);
  float* cTb = (float*)take((size_t)B_N*HH*4);
  f16* Hbuf16 = (f16*)take((size_t)T_LEN*B_N*H_DIM*2);
  float* outp = (float*)d_out;

  auto prep = [&](u16* dst, const float* src, int K, int C, int sk, int sc){
    int n = K*C;
    k_prep<<<(n+255)/256, 256, 0, stream>>>(dst, src, K, C, sk, sc);
  };
  prep(wihF, Wih_f, 64, 400, 1, 64);
  prep(whhF, Whh_f, 100, 400, 1, 100);
  prep(wihB, Wih_b, 64, 400, 1, 64);
  prep(whhB, Whh_b, 100, 400, 1, 100);

  {
    int n;
    n = NCOL_PAD*KH_PAD; k_zf16<<<(n+255)/256,256,0,stream>>>(wattn16, n);
    n = NCOL_PAD*KC_PAD; k_zf16<<<(n+255)/256,256,0,stream>>>(wav16, n);
    n = 800*440; k_pack16<<<(n+255)/256,256,0,stream>>>(wall16, Wih_d, KTOT, 0,   800, 440, 1, 440);
    n = 800*200; k_pack16<<<(n+255)/256,256,0,stream>>>(wall16, Whh_d, KTOT, 440, 800, 200, 1, 200);
    // wattn16[j][n] = W_attn[n][j]  (g[j] = sum_n h[n]*W_attn[n][j])
    n = 200*200; k_pack16<<<(n+255)/256,256,0,stream>>>(wattn16, W_attn, KH_PAD, 0, 200, 200, 200, 1);
    // wav[c][k] = W_av[c][k] packed k-major: B[k][n]=W_av[n][k]
    n = 200*400; k_pack16<<<(n+255)/256,256,0,stream>>>(wav16, W_av, KC_PAD, 0, 200, 400, 1, 400);
  }

  k_encoder<<<256, 512, 0, stream>>>(sentences, src_emb, b_f, b_b,
      (const uint2*)wihF, (const uint2*)whhF, (const uint2*)wihB, (const uint2*)whhB,
      enc_sk, hTf, cTf, hTb, cTb);

  k_transpose<<<B_N, 256, 0, stream>>>(enc_sk, enc_ks);

  k_decoder<<<B_N/ROWS, 512, 0, stream>>>(is_prod, prod_ids, prim_ids, field_ids, parent_t,
      actprod, prim_emb, field_emb, b_d,
      wall16, wattn16, wav16,
      enc_ks, hTf, cTf, hTb, cTb, Hbuf16, outp);
}